// Round 1
// baseline (226.333 us; speedup 1.0000x reference)
//
#include <hip/hip_runtime.h>

// SpatialTransformer: trilinear warp of vol [B,X,Y,Z,1] by dense flow [B,X,Y,Z,3].
// B=2, X=Y=Z=160, fp32 everywhere.

#define DIM 160
#define DD  (DIM * DIM)
#define DDD (DIM * DIM * DIM)
#define BATCH 2
#define TOTAL (BATCH * DDD)

__global__ __launch_bounds__(256) void st_warp_kernel(
    const float* __restrict__ vol,
    const float* __restrict__ flow,
    float* __restrict__ out)
{
    int idx = blockIdx.x * blockDim.x + threadIdx.x;
    if (idx >= TOTAL) return;

    // decompose idx -> (b, x, y, z); z fastest (matches [B,X,Y,Z] row-major)
    int b   = idx / DDD;
    int rem = idx - b * DDD;
    int x   = rem / DD;
    int r2  = rem - x * DD;
    int y   = r2 / DIM;
    int z   = r2 - y * DIM;

    // flow: [B,X,Y,Z,3] contiguous; 12 B per thread, contiguous across the wave
    const float* f = flow + (size_t)idx * 3;
    float fx = f[0];
    float fy = f[1];
    float fz = f[2];

    const float maxf = (float)(DIM - 1);

    // absolute sample location, clipped (matches jnp.clip(loc, 0, d-1))
    float lx = fminf(fmaxf((float)x + fx, 0.0f), maxf);
    float ly = fminf(fmaxf((float)y + fy, 0.0f), maxf);
    float lz = fminf(fmaxf((float)z + fz, 0.0f), maxf);

    // floor -> corner 0 (already in [0, D-1] after the clip above)
    int x0 = (int)floorf(lx);
    int y0 = (int)floorf(ly);
    int z0 = (int)floorf(lz);
    // guard (paranoia; floorf(159.0f)=159)
    x0 = min(max(x0, 0), DIM - 1);
    y0 = min(max(y0, 0), DIM - 1);
    z0 = min(max(z0, 0), DIM - 1);

    int x1 = min(x0 + 1, DIM - 1);
    int y1 = min(y0 + 1, DIM - 1);
    int z1 = min(z0 + 1, DIM - 1);

    // voxelmorph weights: w_lo = float(loc1i) - clipped_loc ; w_hi = 1 - w_lo
    float wx0 = (float)x1 - lx;  float wx1 = 1.0f - wx0;
    float wy0 = (float)y1 - ly;  float wy1 = 1.0f - wy0;
    float wz0 = (float)z1 - lz;  float wz1 = 1.0f - wz0;

    const float* vb = vol + (size_t)b * DDD;

    int bx0 = x0 * DD, bx1 = x1 * DD;
    int by0 = y0 * DIM, by1 = y1 * DIM;

    // 8 corner gathers; z-neighbors are adjacent in memory (good cache locality)
    float v000 = vb[bx0 + by0 + z0];
    float v100 = vb[bx1 + by0 + z0];
    float v010 = vb[bx0 + by1 + z0];
    float v110 = vb[bx1 + by1 + z0];
    float v001 = vb[bx0 + by0 + z1];
    float v101 = vb[bx1 + by0 + z1];
    float v011 = vb[bx0 + by1 + z1];
    float v111 = vb[bx1 + by1 + z1];

    // accumulate in the same corner order as the reference (c = 0..7,
    // bit d of c selects hi corner along dim d; dim0=x, dim1=y, dim2=z)
    float acc;
    acc  = v000 * (wx0 * wy0 * wz0);
    acc += v100 * (wx1 * wy0 * wz0);
    acc += v010 * (wx0 * wy1 * wz0);
    acc += v110 * (wx1 * wy1 * wz0);
    acc += v001 * (wx0 * wy0 * wz1);
    acc += v101 * (wx1 * wy0 * wz1);
    acc += v011 * (wx0 * wy1 * wz1);
    acc += v111 * (wx1 * wy1 * wz1);

    out[idx] = acc;
}

extern "C" void kernel_launch(void* const* d_in, const int* in_sizes, int n_in,
                              void* d_out, int out_size, void* d_ws, size_t ws_size,
                              hipStream_t stream)
{
    const float* vol  = (const float*)d_in[0];
    const float* flow = (const float*)d_in[1];
    float* out = (float*)d_out;

    int blocks = (TOTAL + 255) / 256;
    st_warp_kernel<<<blocks, 256, 0, stream>>>(vol, flow, out);
}